// Round 1
// baseline (2612.344 us; speedup 1.0000x reference)
//
#include <hip/hip_runtime.h>
#include <math.h>

// Problem constants
#define BB 4
#define TT 512
#define FF 257
#define NMIC 4
#define NP 10
#define DM 128
#define C2P 20          // 2*P channels
#define KW 5            // conv taps
#define FPAD 272        // padded f for featT (16*17)

// ---------------------------------------------------------------------------
// K1: per-(b,f) stats over time: mic means (re,im) and inverse power norm.
// stats layout: [b][f][10]: 0..3 = mean_re[mic], 4..7 = mean_im[mic], 8 = inv_norm
// grid: 4 * 65 blocks of 256 threads; 4 f per block, 64 t-threads per f.
// ---------------------------------------------------------------------------
__global__ __launch_bounds__(256) void k1_stats(const float* __restrict__ x,
                                                float* __restrict__ stats) {
    const int b = blockIdx.x / 65;
    const int ftile = blockIdx.x % 65;
    const int tid = threadIdx.x;
    const int fl = tid & 3;          // f within tile
    const int tt = tid >> 2;         // t-thread 0..63
    const int f = ftile * 4 + fl;

    float sr0 = 0.f, sr1 = 0.f, sr2 = 0.f, sr3 = 0.f;
    float si0 = 0.f, si1 = 0.f, si2 = 0.f, si3 = 0.f;
    float ssq = 0.f;
    if (f < FF) {
        for (int t = tt; t < TT; t += 64) {
            const float* px = x + (((size_t)b * TT + t) * FF + f) * 8;
            float4 v0 = *(const float4*)px;
            float4 v1 = *(const float4*)(px + 4);
            sr0 += v0.x; sr1 += v0.y; sr2 += v0.z; sr3 += v0.w;
            si0 += v1.x; si1 += v1.y; si2 += v1.z; si3 += v1.w;
            ssq += v0.x*v0.x + v0.y*v0.y + v0.z*v0.z + v0.w*v0.w
                 + v1.x*v1.x + v1.y*v1.y + v1.z*v1.z + v1.w*v1.w;
        }
    }
    __shared__ float red[256][10];
    red[tid][0] = sr0; red[tid][1] = sr1; red[tid][2] = sr2; red[tid][3] = sr3;
    red[tid][4] = si0; red[tid][5] = si1; red[tid][6] = si2; red[tid][7] = si3;
    red[tid][8] = ssq;
    __syncthreads();
    for (int s = 32; s >= 1; s >>= 1) {
        if (tt < s) {
            for (int c = 0; c < 9; c++) red[tid][c] += red[tid + 4 * s][c];
        }
        __syncthreads();
    }
    if (tt == 0 && f < FF) {
        const float invT = 1.0f / (float)TT;
        float pw = red[tid][8] * invT;
        float* st = stats + ((size_t)b * FF + f) * 10;
        #pragma unroll
        for (int m = 0; m < 4; m++) {
            float mr = red[tid][m] * invT;
            float mi = red[tid][4 + m] * invT;
            st[m] = mr; st[4 + m] = mi;
            pw -= mr * mr + mi * mi;
        }
        st[8] = rsqrtf(fmaxf(pw, 1e-10f));
    }
}

// ---------------------------------------------------------------------------
// K3: one block per (b,t). Computes SCM features for the 5-row time halo,
// conv over taps/channels via register-tiled outer product, fused LayerNorm.
// 256 threads = 16 d-threads (8 d each) x 16 f-threads (17 f each, stride 16).
// ---------------------------------------------------------------------------
__global__ __launch_bounds__(256, 2) void k3_conv_ln(
        const float* __restrict__ x,
        const float* __restrict__ expnt,
        const float* __restrict__ ipdf,
        const float* __restrict__ convw,
        const float* __restrict__ convb,
        const float* __restrict__ lnw,
        const float* __restrict__ lnb,
        const float* __restrict__ stats,
        float* __restrict__ out) {
    const int bt = blockIdx.x;
    const int b = bt >> 9;          // T = 512
    const int t = bt & 511;
    const int tid = threadIdx.x;
    const int ftid = tid & 15;
    const int dtid = tid >> 4;
    const int d0 = dtid * 8;

    __shared__ float xn[5 * FF * 9];      // normalized mic halo, +1 pad (46260 B)
    __shared__ float featT[10 * FPAD];    // feature rows for current pair (10880 B)
    __shared__ float wc[10 * DM];         // weight slice for current pair  (5120 B)
    __shared__ float sef[FF];             // sigmoid(exponent)
    __shared__ float sif[FF];             // sigmoid(IPD_factor)
    __shared__ float wred[8];

    for (int f = tid; f < FF; f += 256) {
        sef[f] = 1.0f / (1.0f + expf(-expnt[f]));
        sif[f] = 1.0f / (1.0f + expf(-ipdf[f]));
    }

    // Phase A: stage x halo into LDS, centered and power-normalized.
    for (int k = 0; k < 5; k++) {
        const int ts = t + k - 2;
        if (ts < 0 || ts >= TT) continue;
        const float* src = x + ((size_t)(b * TT + ts) * FF) * 8;
        const float* stb = stats + (size_t)b * FF * 10;
        for (int idx = tid; idx < FF * 8; idx += 256) {
            const int f = idx >> 3, c = idx & 7;
            const float* st = stb + (size_t)f * 10;
            xn[(k * FF + f) * 9 + c] = (src[idx] - st[c]) * st[8];
        }
    }
    __syncthreads();

    float acc[8][17];
    #pragma unroll
    for (int i = 0; i < 8; i++)
        #pragma unroll
        for (int j = 0; j < 17; j++) acc[i][j] = 0.f;

    for (int p = 0; p < NP; p++) {
        // weight slice: wc[cl*5+k][d] = convw[d][2p+cl][k]
        for (int idx = tid; idx < 10 * DM; idx += 256) {
            const int row = idx >> 7, d = idx & 127;
            const int cl = row / 5, k = row - cl * 5;
            wc[idx] = convw[(size_t)d * (C2P * KW) + (2 * p + cl) * KW + k];
        }
        // feature rows for pair p
        const int ma = (p < 4) ? 0 : (p < 7) ? 1 : (p < 9) ? 2 : 3;
        const int mb = p - ((p < 4) ? 0 : (p < 7) ? 3 : (p < 9) ? 5 : 6);
        for (int pos = tid; pos < 5 * FPAD; pos += 256) {
            const int k = pos / FPAD, f = pos - k * FPAD;
            float fre = 0.f, fim = 0.f;
            const int ts = t + k - 2;
            if (f < FF && ts >= 0 && ts < TT) {
                const float* xm = &xn[(k * FF + f) * 9];
                const float cra = xm[ma],     cia = xm[4 + ma];
                const float crb = xm[mb],     cib = xm[4 + mb];
                const float re = cra * crb + cia * cib;
                const float im = cia * crb - cra * cib;
                const float r = sqrtf(re * re + im * im);
                const float a = r / (powf(r, sef[f]) + 1e-10f);
                const float ang = atan2f(im, re) * sif[f];
                float sn, cs;
                sincosf(ang, &sn, &cs);
                fre = a * cs;
                fim = a * sn;
            }
            featT[k * FPAD + f] = fre;          // channel 2p   (re)
            featT[(5 + k) * FPAD + f] = fim;    // channel 2p+1 (im)
        }
        __syncthreads();

        #pragma unroll
        for (int kk = 0; kk < 10; kk++) {
            float wr[8], fr[17];
            #pragma unroll
            for (int i = 0; i < 8; i++) wr[i] = wc[kk * DM + d0 + i];
            #pragma unroll
            for (int j = 0; j < 17; j++) fr[j] = featT[kk * FPAD + ftid + 16 * j];
            #pragma unroll
            for (int i = 0; i < 8; i++)
                #pragma unroll
                for (int j = 0; j < 17; j++)
                    acc[i][j] = fmaf(wr[i], fr[j], acc[i][j]);
        }
        __syncthreads();
    }

    // Epilogue: bias + LayerNorm over (d, f<257) then write.
    float cb[8];
    #pragma unroll
    for (int i = 0; i < 8; i++) cb[i] = convb[d0 + i];

    float s1 = 0.f, s2 = 0.f;
    const int jmax = (ftid == 0) ? 17 : 16;   // f = ftid + 16*j < 257
    #pragma unroll
    for (int i = 0; i < 8; i++) {
        #pragma unroll
        for (int j = 0; j < 17; j++) {
            acc[i][j] += cb[i];
            if (j < jmax) { s1 += acc[i][j]; s2 += acc[i][j] * acc[i][j]; }
        }
    }
    #pragma unroll
    for (int off = 32; off >= 1; off >>= 1) {
        s1 += __shfl_down(s1, off, 64);
        s2 += __shfl_down(s2, off, 64);
    }
    const int wv = tid >> 6;
    if ((tid & 63) == 0) { wred[wv] = s1; wred[4 + wv] = s2; }
    __syncthreads();
    const float S1 = wred[0] + wred[1] + wred[2] + wred[3];
    const float S2 = wred[4] + wred[5] + wred[6] + wred[7];
    const float Ninv = 1.0f / (float)(DM * FF);
    const float mu = S1 * Ninv;
    const float var = S2 * Ninv - mu * mu;
    const float rstd = rsqrtf(var + 1e-5f);

    float* op = out + (size_t)bt * DM * FF;
    #pragma unroll
    for (int i = 0; i < 8; i++) {
        const int d = d0 + i;
        #pragma unroll
        for (int j = 0; j < 17; j++) {
            const int f = ftid + 16 * j;
            if (f < FF) {
                const size_t o = (size_t)d * FF + f;
                op[o] = (acc[i][j] - mu) * rstd * lnw[o] + lnb[o];
            }
        }
    }
}

extern "C" void kernel_launch(void* const* d_in, const int* in_sizes, int n_in,
                              void* d_out, int out_size, void* d_ws, size_t ws_size,
                              hipStream_t stream) {
    const float* x     = (const float*)d_in[0];
    const float* expnt = (const float*)d_in[1];
    const float* ipdf  = (const float*)d_in[2];
    const float* convw = (const float*)d_in[3];
    const float* convb = (const float*)d_in[4];
    const float* lnw   = (const float*)d_in[5];
    const float* lnb   = (const float*)d_in[6];
    float* out = (float*)d_out;
    float* stats = (float*)d_ws;   // needs 4*257*10*4 = 41120 B

    k1_stats<<<BB * 65, 256, 0, stream>>>(x, stats);
    k3_conv_ln<<<BB * TT, 256, 0, stream>>>(x, expnt, ipdf, convw, convb,
                                            lnw, lnb, stats, out);
}

// Round 3
// 777.450 us; speedup vs baseline: 3.3601x; 3.3601x over previous
//
#include <hip/hip_runtime.h>
#include <math.h>

// Problem constants
#define BB 4
#define TT 512
#define FF 257
#define NMIC 4
#define NP 10
#define DM 128
#define C2P 20          // 2*P channels
#define KW 5            // conv taps
#define FPAD 272        // padded f for featT (16*17)

// ---------------------------------------------------------------------------
// K1: per-(b,f) stats over time: mic means (re,im) and inverse power norm.
// stats layout: [b][f][10]: 0..3 = mean_re[mic], 4..7 = mean_im[mic], 8 = inv_norm
// ---------------------------------------------------------------------------
__global__ __launch_bounds__(256) void k1_stats(const float* __restrict__ x,
                                                float* __restrict__ stats) {
    const int b = blockIdx.x / 65;
    const int ftile = blockIdx.x % 65;
    const int tid = threadIdx.x;
    const int fl = tid & 3;          // f within tile
    const int tt = tid >> 2;         // t-thread 0..63
    const int f = ftile * 4 + fl;

    float sr0 = 0.f, sr1 = 0.f, sr2 = 0.f, sr3 = 0.f;
    float si0 = 0.f, si1 = 0.f, si2 = 0.f, si3 = 0.f;
    float ssq = 0.f;
    if (f < FF) {
        for (int t = tt; t < TT; t += 64) {
            const float* px = x + (((size_t)b * TT + t) * FF + f) * 8;
            float4 v0 = *(const float4*)px;
            float4 v1 = *(const float4*)(px + 4);
            sr0 += v0.x; sr1 += v0.y; sr2 += v0.z; sr3 += v0.w;
            si0 += v1.x; si1 += v1.y; si2 += v1.z; si3 += v1.w;
            ssq += v0.x*v0.x + v0.y*v0.y + v0.z*v0.z + v0.w*v0.w
                 + v1.x*v1.x + v1.y*v1.y + v1.z*v1.z + v1.w*v1.w;
        }
    }
    __shared__ float red[256][10];
    red[tid][0] = sr0; red[tid][1] = sr1; red[tid][2] = sr2; red[tid][3] = sr3;
    red[tid][4] = si0; red[tid][5] = si1; red[tid][6] = si2; red[tid][7] = si3;
    red[tid][8] = ssq;
    __syncthreads();
    for (int s = 32; s >= 1; s >>= 1) {
        if (tt < s) {
            for (int c = 0; c < 9; c++) red[tid][c] += red[tid + 4 * s][c];
        }
        __syncthreads();
    }
    if (tt == 0 && f < FF) {
        const float invT = 1.0f / (float)TT;
        float pw = red[tid][8] * invT;
        float* st = stats + ((size_t)b * FF + f) * 10;
        #pragma unroll
        for (int m = 0; m < 4; m++) {
            float mr = red[tid][m] * invT;
            float mi = red[tid][4 + m] * invT;
            st[m] = mr; st[4 + m] = mi;
            pw -= mr * mr + mi * mi;
        }
        st[8] = rsqrtf(fmaxf(pw, 1e-10f));
    }
}

// ---------------------------------------------------------------------------
// K3: one block per (b,t). SCM features for the 5-row halo, conv via
// register-tiled outer product, fused LayerNorm.
// 512 threads = 32 d-threads (4 d each) x 16 f-threads (17 f each, stride 16).
// acc[4][17] = 68 VGPRs/thread -> no spill (round-1 had acc[8][17]=136 under a
// 128-VGPR cap => scratch spill => 8.9 GB of phantom HBM traffic).
// ---------------------------------------------------------------------------
__global__ __launch_bounds__(512, 2) void k3_conv_ln(
        const float* __restrict__ x,
        const float* __restrict__ expnt,
        const float* __restrict__ ipdf,
        const float* __restrict__ convw,
        const float* __restrict__ convb,
        const float* __restrict__ lnw,
        const float* __restrict__ lnb,
        const float* __restrict__ stats,
        float* __restrict__ out) {
    const int bt = blockIdx.x;
    const int b = bt >> 9;          // T = 512
    const int t = bt & 511;
    const int tid = threadIdx.x;
    const int ftid = tid & 15;
    const int dtid = tid >> 4;      // 0..31
    const int d0 = dtid * 4;

    __shared__ float xn[5 * FF * 9];      // normalized mic halo (46260 B)
    __shared__ float featT[10 * FPAD];    // feature rows for current pair (10880 B)
    __shared__ float wc[10 * DM];         // weight slice for current pair  (5120 B)
    __shared__ float sef[FF];             // sigmoid(exponent)
    __shared__ float sif[FF];             // sigmoid(IPD_factor)
    __shared__ float wred[16];

    for (int f = tid; f < FF; f += 512) {
        sef[f] = 1.0f / (1.0f + __expf(-expnt[f]));
        sif[f] = 1.0f / (1.0f + __expf(-ipdf[f]));
    }

    // Phase A: stage x halo into LDS, centered and power-normalized.
    for (int k = 0; k < 5; k++) {
        const int ts = t + k - 2;
        if (ts < 0 || ts >= TT) continue;
        const float* src = x + ((size_t)(b * TT + ts) * FF) * 8;
        const float* stb = stats + (size_t)b * FF * 10;
        for (int idx = tid; idx < FF * 8; idx += 512) {
            const int f = idx >> 3, c = idx & 7;
            const float* st = stb + (size_t)f * 10;
            xn[(k * FF + f) * 9 + c] = (src[idx] - st[c]) * st[8];
        }
    }
    __syncthreads();

    float acc[4][17];
    #pragma unroll
    for (int i = 0; i < 4; i++)
        #pragma unroll
        for (int j = 0; j < 17; j++) acc[i][j] = 0.f;

    for (int p = 0; p < NP; p++) {
        // weight slice: wc[cl*5+k][d] = convw[d][2p+cl][k]
        for (int idx = tid; idx < 10 * DM; idx += 512) {
            const int row = idx >> 7, d = idx & 127;
            const int cl = row / 5, k = row - cl * 5;
            wc[idx] = convw[(size_t)d * (C2P * KW) + (2 * p + cl) * KW + k];
        }
        // feature rows for pair p
        const int ma = (p < 4) ? 0 : (p < 7) ? 1 : (p < 9) ? 2 : 3;
        const int mb = p - ((p < 4) ? 0 : (p < 7) ? 3 : (p < 9) ? 5 : 6);
        for (int pos = tid; pos < 5 * FPAD; pos += 512) {
            const int k = pos / FPAD, f = pos - k * FPAD;
            float fre = 0.f, fim = 0.f;
            const int ts = t + k - 2;
            if (f < FF && ts >= 0 && ts < TT) {
                const float* xm = &xn[(k * FF + f) * 9];
                const float cra = xm[ma],     cia = xm[4 + ma];
                const float crb = xm[mb],     cib = xm[4 + mb];
                const float re = cra * crb + cia * cib;
                const float im = cia * crb - cra * cib;
                const float r = sqrtf(re * re + im * im);
                // r^s via hw exp2/log2; r=0 -> log2=-inf -> s*(-inf)=-inf -> exp2=0 (matches ref)
                const float bp = exp2f(sef[f] * __log2f(r));
                const float a = r / (bp + 1e-10f);
                const float ang = atan2f(im, re) * sif[f];
                float sn, cs;
                __sincosf(ang, &sn, &cs);
                fre = a * cs;
                fim = a * sn;
            }
            featT[k * FPAD + f] = fre;          // channel 2p   (re)
            featT[(5 + k) * FPAD + f] = fim;    // channel 2p+1 (im)
        }
        __syncthreads();

        #pragma unroll
        for (int kk = 0; kk < 10; kk++) {
            float wr[4], fr[17];
            #pragma unroll
            for (int i = 0; i < 4; i++) wr[i] = wc[kk * DM + d0 + i];
            #pragma unroll
            for (int j = 0; j < 17; j++) fr[j] = featT[kk * FPAD + ftid + 16 * j];
            #pragma unroll
            for (int i = 0; i < 4; i++)
                #pragma unroll
                for (int j = 0; j < 17; j++)
                    acc[i][j] = fmaf(wr[i], fr[j], acc[i][j]);
        }
        __syncthreads();
    }

    // Epilogue: bias + LayerNorm over (d, f<257) then write.
    float cb[4];
    #pragma unroll
    for (int i = 0; i < 4; i++) cb[i] = convb[d0 + i];

    float s1 = 0.f, s2 = 0.f;
    const int jmax = (ftid == 0) ? 17 : 16;   // f = ftid + 16*j < 257
    #pragma unroll
    for (int i = 0; i < 4; i++) {
        #pragma unroll
        for (int j = 0; j < 17; j++) {
            acc[i][j] += cb[i];
            if (j < jmax) { s1 += acc[i][j]; s2 += acc[i][j] * acc[i][j]; }
        }
    }
    #pragma unroll
    for (int off = 32; off >= 1; off >>= 1) {
        s1 += __shfl_down(s1, off, 64);
        s2 += __shfl_down(s2, off, 64);
    }
    const int wv = tid >> 6;                  // 8 waves
    if ((tid & 63) == 0) { wred[wv] = s1; wred[8 + wv] = s2; }
    __syncthreads();
    float S1 = 0.f, S2 = 0.f;
    #pragma unroll
    for (int w = 0; w < 8; w++) { S1 += wred[w]; S2 += wred[8 + w]; }
    const float Ninv = 1.0f / (float)(DM * FF);
    const float mu = S1 * Ninv;
    const float var = S2 * Ninv - mu * mu;
    const float rstd = rsqrtf(var + 1e-5f);

    float* op = out + (size_t)bt * DM * FF;
    #pragma unroll
    for (int i = 0; i < 4; i++) {
        const int d = d0 + i;
        #pragma unroll
        for (int j = 0; j < 17; j++) {
            const int f = ftid + 16 * j;
            if (f < FF) {
                const size_t o = (size_t)d * FF + f;
                op[o] = (acc[i][j] - mu) * rstd * lnw[o] + lnb[o];
            }
        }
    }
}

extern "C" void kernel_launch(void* const* d_in, const int* in_sizes, int n_in,
                              void* d_out, int out_size, void* d_ws, size_t ws_size,
                              hipStream_t stream) {
    const float* x     = (const float*)d_in[0];
    const float* expnt = (const float*)d_in[1];
    const float* ipdf  = (const float*)d_in[2];
    const float* convw = (const float*)d_in[3];
    const float* convb = (const float*)d_in[4];
    const float* lnw   = (const float*)d_in[5];
    const float* lnb   = (const float*)d_in[6];
    float* out = (float*)d_out;
    float* stats = (float*)d_ws;   // needs 4*257*10*4 = 41120 B

    k1_stats<<<BB * 65, 256, 0, stream>>>(x, stats);
    k3_conv_ln<<<BB * TT, 512, 0, stream>>>(x, expnt, ipdf, convw, convb,
                                            lnw, lnb, stats, out);
}